// Round 4
// baseline (479.373 us; speedup 1.0000x reference)
//
#include <hip/hip_runtime.h>

// SparseConv2D: 32x112x112x128 fp32 NHWC, 3x3 SAME, 126 out ch x 5 taps.
// Implicit GEMM on bf16 MFMA, dense-9-tap. M=112 (one row), N=128, K=9*128.
// R7: bf16 prepass + global_load_lds A-staging.
//  - conv_pre: fp32 input -> bf16 Ain[row][cc4][quad4][114px][8ch] (x-halo
//    zero-padded), 104.6 MB in ws, same XCD swizzle as conv for L2 affinity.
//  - conv_main: A staged by 6x global_load_lds(16B)/thread/cc (no pf regs, no
//    f2bf VALU, no ds_write). Regs ~180 -> ~150 => __launch_bounds__(256,3),
//    3 waves/SIMD. B frags (18) issued before the stage so no vmcnt wait
//    drains the stage DMA.
//  - Fallback to the proven R6 kernel when ws_size < ~105 MB.

typedef __attribute__((ext_vector_type(8))) __bf16 bf16x8;
typedef __attribute__((ext_vector_type(4))) float f32x4;
typedef __attribute__((ext_vector_type(8))) unsigned short ushort8;

__device__ __forceinline__ unsigned short f2bf(float f) {
  unsigned int u = __builtin_bit_cast(unsigned int, f);
  u += 0x7fffu + ((u >> 16) & 1u);   // RNE (inputs are finite normals)
  return (unsigned short)(u >> 16);
}

__device__ __forceinline__ void async_copy16(void* lds, const void* g) {
  __builtin_amdgcn_global_load_lds(
      (const __attribute__((address_space(1))) unsigned int*)g,
      (__attribute__((address_space(3))) unsigned int*)lds, 16, 0, 0);
}

// ---- workspace layout ----
// [0, 294912)                 Bws  (9*4*128*32 bf16)
// [294912, +104644608)        Ain  (3584 rows * 29184 B)
// [+29184]                    zero page (one full row image)
#define BWS_BYTES 294912
#define ROW_BYTES 29184                      // 4cc * 4q * 114 * 8ch * 2B
#define ROW_USH   14592
#define AIN_BYTES (3584LL * ROW_BYTES)
#define WS_NEED   ((size_t)BWS_BYTES + (size_t)AIN_BYTES + (size_t)ROW_BYTES)

// Bws[p][cc][n][c] bf16: dense kernel, n in [0,128) (126..127 zero), c in [0,32)
__global__ __launch_bounds__(256) void build_B(const float* __restrict__ sk,
                                               const int* __restrict__ patterns,
                                               unsigned short* __restrict__ Bws) {
  int idx = blockIdx.x * 256 + threadIdx.x;
  if (idx >= 9 * 128 * 128) return;
  int c = idx & 127;
  int n = (idx >> 7) & 127;
  int p = idx >> 14;
  float v = 0.f;
  if (n < 126) {
#pragma unroll
    for (int j = 0; j < 5; ++j)
      if (patterns[n * 5 + j] == p) v = sk[(j * 128 + c) * 126 + n];
  }
  int cc = c >> 5, cl = c & 31;
  Bws[(((p * 4 + cc) * 128) + n) * 32 + cl] = f2bf(v);
}

// fp32 (img,y,x,128ch) -> bf16 Ain[row][cc][q][114][8], px = x+1, px 0/113 zero.
__global__ __launch_bounds__(256) void conv_pre(const float* __restrict__ in,
                                                unsigned short* __restrict__ Ain) {
  const int bid = ((blockIdx.x & 7) * 448) + (blockIdx.x >> 3);
  const float* inrow = in + (size_t)bid * 112 * 128;
  unsigned short* orow = Ain + (size_t)bid * ROW_USH;
  const int tid = threadIdx.x;
#pragma unroll
  for (int it = 0; it < 8; ++it) {
    int j = tid + it * 256;
    if (j < 1824) {                       // 114 px * 16 (cc,q)
      int px = j >> 4;
      int ccq = j & 15;                   // ch offset = ccq*8
      int gx = px - 1;
      ushort8 s = (ushort8)0;
      if ((unsigned)gx < 112u) {
        const float* p = inrow + (size_t)gx * 128 + ccq * 8;
        float4 a = *(const float4*)p;
        float4 b = *(const float4*)(p + 4);
        s[0] = f2bf(a.x); s[1] = f2bf(a.y); s[2] = f2bf(a.z); s[3] = f2bf(a.w);
        s[4] = f2bf(b.x); s[5] = f2bf(b.y); s[6] = f2bf(b.z); s[7] = f2bf(b.w);
      }
      int cc = ccq >> 2, q = ccq & 3;
      *(ushort8*)(orow + cc * 3648 + q * 912 + px * 8) = s;
    }
  }
}

__global__ __launch_bounds__(256, 3) void conv_main(const unsigned short* __restrict__ Ain,
                                                    const unsigned short* __restrict__ zp,
                                                    const unsigned short* __restrict__ Bws,
                                                    const float* __restrict__ bias,
                                                    float* __restrict__ out) {
  // A dbuf: per buf 1536 16B-pieces (3 rows x 456 used + 168 pad), layout
  // [r][q][114][8] -> frag read = 16 lanes x 16B contiguous in a q-plane.
  __shared__ unsigned short Alds[2 * 1536 * 8];   // 49,152 B

  const int tid = threadIdx.x;
  const int bid = ((blockIdx.x & 7) * 448) + (blockIdx.x >> 3);
  const int nimg = bid / 112;
  const int y = bid - nimg * 112;
  const int lane = tid & 63;
  const int w = tid >> 6;           // wave id: output cols [32w, 32w+32)
  const int quad = lane >> 4;
  const int lrow = lane & 15;

  const unsigned short* rp0;
  const unsigned short* rp1 = Ain + (size_t)bid * ROW_USH;
  const unsigned short* rp2;
  rp0 = (y > 0)   ? (rp1 - ROW_USH) : zp;
  rp2 = (y < 111) ? (rp1 + ROW_USH) : zp;

  f32x4 acc[7][2];
#pragma unroll
  for (int mt = 0; mt < 7; ++mt) { acc[mt][0] = (f32x4)0.f; acc[mt][1] = (f32x4)0.f; }

  auto stage = [&](int cc, int buf) {
    const unsigned short* c0 = rp0 + cc * 3648;
    const unsigned short* c1 = rp1 + cc * 3648;
    const unsigned short* c2 = rp2 + cc * 3648;
#pragma unroll
    for (int it = 0; it < 6; ++it) {
      int i = tid + it * 256;                 // [0,1536)
      bool b1 = (i >= 456), b2 = (i >= 912);
      int rem = i - (b2 ? 912 : (b1 ? 456 : 0));
      const unsigned short* base = b2 ? c2 : (b1 ? c1 : c0);
      const unsigned short* src = (i < 1368) ? (base + rem * 8) : zp;
      async_copy16((void*)&Alds[(size_t)buf * 12288 + (size_t)i * 8], (const void*)src);
    }
  };

  stage(0, 0);
  __syncthreads();

#pragma unroll 1
  for (int cc = 0; cc < 4; ++cc) {
    const int buf = cc & 1;
    // B frags: 9 taps x 2 n-frags from L2-hot Bws. Issued BEFORE the stage so
    // waiting on b[p] never drains the stage DMA (vmcnt oldest-first).
    bf16x8 b[9][2];
#pragma unroll
    for (int p = 0; p < 9; ++p)
#pragma unroll
      for (int j = 0; j < 2; ++j)
        b[p][j] = *(const bf16x8*)(Bws +
            (((size_t)(p * 4 + cc) * 128 + w * 32 + j * 16 + lrow) * 32 + quad * 8));

    if (cc < 3) stage(cc + 1, buf ^ 1);   // DMA in flight during the MFMAs

#pragma unroll
    for (int p = 0; p < 9; ++p) {
      const int r = p / 3;          // dy = r-1
      const int px = p - r * 3;     // dx = px-1
      const int abase = buf * 12288 + r * 3648 + quad * 912 + (px + lrow) * 8;
#pragma unroll
      for (int mt = 0; mt < 7; ++mt) {
        bf16x8 a = *(const bf16x8*)&Alds[abase + mt * 128];
        acc[mt][0] = __builtin_amdgcn_mfma_f32_16x16x32_bf16(a, b[p][0], acc[mt][0], 0, 0, 0);
        acc[mt][1] = __builtin_amdgcn_mfma_f32_16x16x32_bf16(a, b[p][1], acc[mt][1], 0, 0, 0);
      }
    }

    if (cc < 3) __syncthreads();   // drains DMA (vmcnt) + flips buffers
  }

  // epilogue: C/D layout col = lane&15 (N), row = quad*4 + reg (M)
  const int k0 = w * 32 + lrow;
  const int k1 = k0 + 16;
  const float bv0 = bias[k0 < 126 ? k0 : 125];
  const float bv1 = bias[k1 < 126 ? k1 : 125];
  float* outrow = out + (size_t)bid * 112 * 126;
#pragma unroll
  for (int mt = 0; mt < 7; ++mt) {
#pragma unroll
    for (int rg = 0; rg < 4; ++rg) {
      int x = mt * 16 + quad * 4 + rg;
      float* o = outrow + (size_t)x * 126;
      if (k0 < 126) { float v = acc[mt][0][rg] + bv0; o[k0] = v > 0.f ? v : 0.f; }
      if (k1 < 126) { float v = acc[mt][1][rg] + bv1; o[k1] = v > 0.f ? v : 0.f; }
    }
  }
}

// ---------------- R6 fallback (ws too small) ----------------
__global__ __launch_bounds__(256, 2) void conv_main_fb(const float* __restrict__ in,
                                                       const unsigned short* __restrict__ Bws,
                                                       const float* __restrict__ bias,
                                                       float* __restrict__ out) {
  __shared__ unsigned short Alds[2 * 4 * 342 * 8];   // 43,776 B

  const int tid = threadIdx.x;
  const int bid = ((blockIdx.x & 7) * 448) + (blockIdx.x >> 3);
  const int nimg = bid / 112;
  const int y = bid - nimg * 112;
  const int lane = tid & 63;
  const int w = tid >> 6;
  const int quad = lane >> 4;
  const int lrow = lane & 15;

  const float* inb = in + (size_t)nimg * 112 * 112 * 128;

  f32x4 acc[7][2];
#pragma unroll
  for (int mt = 0; mt < 7; ++mt) { acc[mt][0] = (f32x4)0.f; acc[mt][1] = (f32x4)0.f; }

  float4 pf[11];
  auto loadA = [&](int cc) {
#pragma unroll
    for (int it = 0; it < 11; ++it) {
      int i = tid + it * 256;
      float4 v = make_float4(0.f, 0.f, 0.f, 0.f);
      if (i < 2736) {
        int c4 = i & 7;
        int rest = i >> 3;
        int r = rest / 114;
        int hx = rest - r * 114;
        int gy = y + r - 1;
        int gx = hx - 1;
        if ((unsigned)gy < 112u && (unsigned)gx < 112u)
          v = *(const float4*)(inb + ((size_t)gy * 112 + gx) * 128 + cc * 32 + c4 * 4);
      }
      pf[it] = v;
    }
  };
  auto writeA = [&](int b) {
#pragma unroll
    for (int it = 0; it < 11; ++it) {
      int i = tid + it * 256;
      if (i < 2736) {
        int c4 = i & 7;
        int rest = i >> 3;
        int q = c4 >> 1, h = c4 & 1;
        ushort4 s;
        s.x = f2bf(pf[it].x); s.y = f2bf(pf[it].y);
        s.z = f2bf(pf[it].z); s.w = f2bf(pf[it].w);
        *(ushort4*)&Alds[(((b * 4 + q) * 342) + rest) * 8 + h * 4] = s;
      }
    }
  };

  loadA(0);
  writeA(0);
  __syncthreads();

#pragma unroll 1
  for (int cc = 0; cc < 4; ++cc) {
    const int cur = cc & 1;
    bf16x8 b[9][2];
#pragma unroll
    for (int p = 0; p < 9; ++p)
#pragma unroll
      for (int j = 0; j < 2; ++j)
        b[p][j] = *(const bf16x8*)(Bws +
            (((size_t)(p * 4 + cc) * 128 + w * 32 + j * 16 + lrow) * 32 + quad * 8));

    if (cc < 3) loadA(cc + 1);

    const unsigned short* Ab = &Alds[(size_t)(cur * 4 + quad) * 2736];
#pragma unroll
    for (int p = 0; p < 9; ++p) {
      const int r = p / 3;
      const int px = p - r * 3;
      const int abase = (r * 114 + px + lrow) * 8;
#pragma unroll
      for (int mt = 0; mt < 7; ++mt) {
        bf16x8 a = *(const bf16x8*)&Ab[abase + mt * 128];
        acc[mt][0] = __builtin_amdgcn_mfma_f32_16x16x32_bf16(a, b[p][0], acc[mt][0], 0, 0, 0);
        acc[mt][1] = __builtin_amdgcn_mfma_f32_16x16x32_bf16(a, b[p][1], acc[mt][1], 0, 0, 0);
      }
    }

    if (cc < 3) {
      writeA(cur ^ 1);
      __syncthreads();
    }
  }

  const int k0 = w * 32 + lrow;
  const int k1 = k0 + 16;
  const float bv0 = bias[k0 < 126 ? k0 : 125];
  const float bv1 = bias[k1 < 126 ? k1 : 125];
  float* outrow = out + (size_t)bid * 112 * 126;
#pragma unroll
  for (int mt = 0; mt < 7; ++mt) {
#pragma unroll
    for (int rg = 0; rg < 4; ++rg) {
      int x = mt * 16 + quad * 4 + rg;
      float* o = outrow + (size_t)x * 126;
      if (k0 < 126) { float v = acc[mt][0][rg] + bv0; o[k0] = v > 0.f ? v : 0.f; }
      if (k1 < 126) { float v = acc[mt][1][rg] + bv1; o[k1] = v > 0.f ? v : 0.f; }
    }
  }
}

extern "C" void kernel_launch(void* const* d_in, const int* in_sizes, int n_in,
                              void* d_out, int out_size, void* d_ws, size_t ws_size,
                              hipStream_t stream) {
  const float* in = (const float*)d_in[0];        // (32,112,112,128) fp32
  const float* sk = (const float*)d_in[1];        // (5,128,126) fp32
  const float* bias = (const float*)d_in[2];      // (126,) fp32
  const int* patterns = (const int*)d_in[3];      // (126,5) int32
  float* out = (float*)d_out;                     // (32,112,112,126) fp32
  unsigned short* Bws = (unsigned short*)d_ws;

  build_B<<<dim3(576), dim3(256), 0, stream>>>(sk, patterns, Bws);

  if (ws_size >= WS_NEED) {
    unsigned short* Ain = (unsigned short*)((char*)d_ws + BWS_BYTES);
    unsigned short* zp  = (unsigned short*)((char*)d_ws + BWS_BYTES + AIN_BYTES);
    hipMemsetAsync(zp, 0, ROW_BYTES, stream);
    conv_pre<<<dim3(32 * 112), dim3(256), 0, stream>>>(in, Ain);
    conv_main<<<dim3(32 * 112), dim3(256), 0, stream>>>(Ain, zp, Bws, bias, out);
  } else {
    conv_main_fb<<<dim3(32 * 112), dim3(256), 0, stream>>>(in, Bws, bias, out);
  }
}